// Round 6
// baseline (163.254 us; speedup 1.0000x reference)
//
#include <hip/hip_runtime.h>

#define N_SP 3136   // H*W
#define NP   3200   // padded N (25 x 128)
#define NT   25     // attn j-tiles of 128
#define C_CH 256
#define CQ   32
#define NB   4
// 1 / (exp(sqrt(3))*sqrt(3136/256) + 2*sqrt(6))
#define INV_BOUND 0.04051569f
#define LOG2E 1.44269504f

typedef __attribute__((ext_vector_type(8))) short bf16x8;
typedef __attribute__((ext_vector_type(4))) float f32x4;
typedef __attribute__((ext_vector_type(2))) unsigned int u32x2;
typedef unsigned short u16;
typedef unsigned int   u32;

#define MFMA16(a,b,c) __builtin_amdgcn_mfma_f32_16x16x32_bf16(a,b,c,0,0,0)

__device__ __forceinline__ u16 f2b(float f) {
    u32 u = __builtin_bit_cast(u32, f);
    u += 0x7fffu + ((u >> 16) & 1u);   // RTNE
    return (u16)(u >> 16);
}
__device__ __forceinline__ u32 pk_bf16(float a, float b) {
    return (u32)f2b(a) | ((u32)f2b(b) << 16);
}

// ---------------------------------------------------------------------------
// stage1: fused xT transpose (blocks 0..783), W->bf16 (784..863), norm (864)
// ---------------------------------------------------------------------------
__global__ __launch_bounds__(256) void stage1_kernel(
    const float* __restrict__ x, const float* __restrict__ Wq,
    const float* __restrict__ Wk, const float* __restrict__ Wv,
    u16* __restrict__ xT, u16* __restrict__ Wqb, u16* __restrict__ Wkb,
    u16* __restrict__ Wvb, float* __restrict__ scale_out)
{
    __shared__ float smem[64 * 65];
    const int t = threadIdx.x;
    const int bid = blockIdx.x;

    if (bid < 784) {                       // xT[b][n][c] = bf16(x[b][c][n])
        float (*tile)[65] = (float(*)[65])smem;
        const int ct = bid & 3, nt = (bid >> 2) % 49, b = bid / 196;
        const int c0 = ct * 64, n0 = nt * 64;
        const int cc = t >> 4, nn4 = (t & 15) * 4;
        #pragma unroll
        for (int i = 0; i < 4; ++i) {
            int cl = cc + i * 16;
            float4 v = *(const float4*)(x + (size_t)(b * C_CH + c0 + cl) * N_SP + n0 + nn4);
            tile[cl][nn4] = v.x; tile[cl][nn4 + 1] = v.y;
            tile[cl][nn4 + 2] = v.z; tile[cl][nn4 + 3] = v.w;
        }
        __syncthreads();
        const int c4 = (t & 15) * 4, nn = t >> 4;
        #pragma unroll
        for (int i = 0; i < 4; ++i) {
            int nl = nn + i * 16;
            ushort4 o;
            o.x = f2b(tile[c4 + 0][nl]); o.y = f2b(tile[c4 + 1][nl]);
            o.z = f2b(tile[c4 + 2][nl]); o.w = f2b(tile[c4 + 3][nl]);
            *(ushort4*)(xT + (size_t)(b * N_SP + n0 + nl) * C_CH + c0 + c4) = o;
        }
    } else if (bid < 864) {                // W f32 -> bf16
        int idx = (bid - 784) * 256 + t;
        const float* src; u16* dst; int off;
        if (idx < 2048)      { src = Wq; dst = Wqb; off = idx; }
        else if (idx < 4096) { src = Wk; dst = Wkb; off = idx - 2048; }
        else                 { src = Wv; dst = Wvb; off = idx - 4096; }
        float4 v = *(const float4*)(src + off * 4);
        ushort4 o; o.x = f2b(v.x); o.y = f2b(v.y); o.z = f2b(v.z); o.w = f2b(v.w);
        *(ushort4*)(dst + off * 4) = o;
    } else {                               // norm -> scale
        float* red = smem;
        float u2 = 0.f;
        for (int i = t; i < CQ * C_CH; i += 256) { float w = Wq[i]; u2 += w * w; }
        red[t] = u2; __syncthreads();
        #pragma unroll
        for (int s = 128; s > 0; s >>= 1) { if (t < s) red[t] += red[t + s]; __syncthreads(); }
        float u2t = red[0]; __syncthreads();
        float vn2 = 0.f;
        for (int o = 0; o < CQ; ++o)   { float w = Wk[o * C_CH + t]; vn2 += w * w; }
        float wn2 = 0.f;
        for (int o = 0; o < C_CH; ++o) { float w = Wv[o * C_CH + t]; wn2 += w * w; }
        red[t] = fmaxf(vn2, wn2); __syncthreads();
        #pragma unroll
        for (int s = 128; s > 0; s >>= 1) { if (t < s) red[t] = fmaxf(red[t], red[t + s]); __syncthreads(); }
        if (t == 0) scale_out[0] = 1.0f / (sqrtf(u2t) * sqrtf(red[0]));
    }
}

// ---------------------------------------------------------------------------
// qkv via MFMA, 5-way row split (split0: q+k, split1..4: 64 V-rows each).
// kT/Vb use padded stride NP; blocks 980..983 zero the pad region.
// qT pre-multiplied by scale*log2(e); emits qnorm[b][n], kmax[b] (atomicMax).
// ---------------------------------------------------------------------------
__global__ __launch_bounds__(256) void qkv_mfma(
    const u16* __restrict__ xT, const u16* __restrict__ Wqb,
    const u16* __restrict__ Wkb, const u16* __restrict__ Wvb,
    const float* __restrict__ bq, const float* __restrict__ bk,
    const float* __restrict__ bv, const float* __restrict__ scale_p,
    u16* __restrict__ qT, u16* __restrict__ kT, u16* __restrict__ Vb,
    float* __restrict__ qnorm, float* __restrict__ kmax)
{
    const int t = threadIdx.x;

    if (blockIdx.x >= 980) {               // zero j-pad [3136, 3200)
        const int b = blockIdx.x - 980;
        uint4 z = make_uint4(0u, 0u, 0u, 0u);
        *(uint4*)(kT + ((size_t)b * NP + 3136) * CQ + t * 8) = z;   // 64 rows x 32
        u16* vrow = Vb + ((size_t)b * C_CH + t) * NP + 3136;        // c = t, 64 elems
        #pragma unroll
        for (int i = 0; i < 8; ++i) *(uint4*)(vrow + i * 8) = z;
        return;
    }

    const int split = blockIdx.x / 196, tile = blockIdx.x % 196;
    const int b = tile / 49, nt = tile % 49;
    const int w = t >> 6, li = t & 15, g = (t >> 4) & 3;
    const int n = nt * 64 + w * 16 + li;
    const f32x4 zero = {0.f, 0.f, 0.f, 0.f};

    bf16x8 xf[8];
    #pragma unroll
    for (int ks = 0; ks < 8; ++ks)
        xf[ks] = *(const bf16x8*)(xT + (size_t)(b * N_SP + n) * C_CH + ks * 32 + 8 * g);

    if (split == 0) {
        f32x4 aq0 = zero, aq1 = zero, ak0 = zero, ak1 = zero;
        #pragma unroll
        for (int ks = 0; ks < 8; ++ks) {
            bf16x8 w0 = *(const bf16x8*)(Wqb + li * C_CH + ks * 32 + 8 * g);
            bf16x8 w1 = *(const bf16x8*)(Wqb + (16 + li) * C_CH + ks * 32 + 8 * g);
            bf16x8 w2 = *(const bf16x8*)(Wkb + li * C_CH + ks * 32 + 8 * g);
            bf16x8 w3 = *(const bf16x8*)(Wkb + (16 + li) * C_CH + ks * 32 + 8 * g);
            aq0 = MFMA16(w0, xf[ks], aq0);
            aq1 = MFMA16(w1, xf[ks], aq1);
            ak0 = MFMA16(w2, xf[ks], ak0);
            ak1 = MFMA16(w3, xf[ks], ak1);
        }
        const float scf = scale_p[0] * LOG2E;
        f32x4 bq0 = *(const f32x4*)(bq + 4 * g);
        f32x4 bq1 = *(const f32x4*)(bq + 16 + 4 * g);
        f32x4 bk0 = *(const f32x4*)(bk + 4 * g);
        f32x4 bk1 = *(const f32x4*)(bk + 16 + 4 * g);
        float qn2 = 0.f, kn2 = 0.f;
        ushort4 s0, s1;
        #pragma unroll
        for (int r = 0; r < 4; ++r) {
            float q0 = (aq0[r] + bq0[r]) * scf;
            float q1 = (aq1[r] + bq1[r]) * scf;
            qn2 += q0 * q0 + q1 * q1;
            ((u16*)&s0)[r] = f2b(q0); ((u16*)&s1)[r] = f2b(q1);
        }
        *(ushort4*)(qT + (size_t)(b * N_SP + n) * CQ + 4 * g)      = s0;
        *(ushort4*)(qT + (size_t)(b * N_SP + n) * CQ + 16 + 4 * g) = s1;
        #pragma unroll
        for (int r = 0; r < 4; ++r) {
            float k0 = ak0[r] + bk0[r];
            float k1 = ak1[r] + bk1[r];
            kn2 += k0 * k0 + k1 * k1;
            ((u16*)&s0)[r] = f2b(k0); ((u16*)&s1)[r] = f2b(k1);
        }
        *(ushort4*)(kT + (size_t)(b * NP + n) * CQ + 4 * g)      = s0;
        *(ushort4*)(kT + (size_t)(b * NP + n) * CQ + 16 + 4 * g) = s1;

        qn2 += __shfl_xor(qn2, 16); qn2 += __shfl_xor(qn2, 32);
        kn2 += __shfl_xor(kn2, 16); kn2 += __shfl_xor(kn2, 32);
        if (g == 0) qnorm[b * N_SP + n] = sqrtf(qn2);
        float kn = sqrtf(kn2);
        #pragma unroll
        for (int d = 1; d < 16; d <<= 1) kn = fmaxf(kn, __shfl_xor(kn, d));
        if ((t & 63) == 0) atomicMax((int*)(kmax + b), __float_as_int(kn));
    } else {
        const int r0 = (split - 1) * 64;
        f32x4 a[4] = {zero, zero, zero, zero};
        #pragma unroll
        for (int ks = 0; ks < 8; ++ks) {
            #pragma unroll
            for (int fr = 0; fr < 4; ++fr) {
                bf16x8 wf = *(const bf16x8*)(Wvb + (size_t)(r0 + fr * 16 + li) * C_CH + ks * 32 + 8 * g);
                a[fr] = MFMA16(wf, xf[ks], a[fr]);
            }
        }
        #pragma unroll
        for (int fr = 0; fr < 4; ++fr) {
            f32x4 bb = *(const f32x4*)(bv + r0 + fr * 16 + 4 * g);
            #pragma unroll
            for (int r = 0; r < 4; ++r)
                Vb[(size_t)(b * C_CH + r0 + fr * 16 + 4 * g + r) * NP + n] = f2b(a[fr][r] + bb[r]);
        }
    }
}

// ---------------------------------------------------------------------------
// Attention: 392 blocks x 512 thr (8 waves). 128-j tiles (25 iters), padded N.
// Wave w: S^T for j-frags {2(w&3), 2(w&3)+1}, q-half w>>2 -> packed b64 into
// XOR-swizzled P (16KB dbuf); PV slice = 32 ch, both q-frags, K/V prefetched
// unconditionally (branch-free) one tile ahead. 1 barrier/tile.
// ---------------------------------------------------------------------------
__global__ __launch_bounds__(512, 4) void attn_mfma(
    const u16* __restrict__ qT, const u16* __restrict__ kT,
    const u16* __restrict__ Vb, const float* __restrict__ x,
    const float* __restrict__ gamma_p, const float* __restrict__ qnorm,
    const float* __restrict__ kmax, float* __restrict__ out)
{
    __shared__ __align__(16) unsigned char P[2][32 * 256];   // 16 KB, swizzled
    __shared__ float red[8][16];
    __shared__ __align__(16) float red_final[32];

    const int t = threadIdx.x;
    const int w = t >> 6, li = t & 15, g = (t >> 4) & 3;
    const int qf = w >> 2, jh = w & 3;
    const int f0 = 2 * jh, f1 = f0 + 1;      // this wave's 16-j frags in tile
    const int cw = w * 32;                   // PV channel base
    const int sw = (li & 7) << 4;            // XOR swizzle

    const int xcd = blockIdx.x & 7, idx = blockIdx.x >> 3;   // 392 = 8*49
    const int b  = xcd >> 1;
    const int i0 = ((xcd & 1) * 49 + idx) * 32;

    const u16* qTb = qT + (size_t)b * N_SP * CQ;
    const u16* kTb = kT + (size_t)b * NP * CQ;
    const u16* Vbb = Vb + ((size_t)b * C_CH + cw) * NP;
    const float kmb = kmax[b];
    const f32x4 zero = {0.f, 0.f, 0.f, 0.f};

    const bf16x8 qfS = *(const bf16x8*)(qTb + (size_t)(i0 + qf * 16 + li) * CQ + 8 * g);
    const float  mrS = qnorm[b * N_SP + i0 + qf * 16 + li] * kmb;

    const int pwOff0 = (qf * 16 + li) * 256 + ((f0 * 32 + 8 * g) ^ sw);
    const int pwOff1 = (qf * 16 + li) * 256 + ((f1 * 32 + 8 * g) ^ sw);
    const int prRow0 = li * 256, prRow1 = (16 + li) * 256;

    f32x4 acc[2][2];
    acc[0][0] = zero; acc[0][1] = zero; acc[1][0] = zero; acc[1][1] = zero;
    float ls = 0.f;

    // prefetch tile 0 (K rows + V frags)
    bf16x8 kf0 = *(const bf16x8*)(kTb + (size_t)(f0 * 16 + li) * CQ + 8 * g);
    bf16x8 kf1 = *(const bf16x8*)(kTb + (size_t)(f1 * 16 + li) * CQ + 8 * g);
    bf16x8 vf[2][4];
    #pragma unroll
    for (int cf = 0; cf < 2; ++cf)
        #pragma unroll
        for (int ks = 0; ks < 4; ++ks)
            vf[cf][ks] = *(const bf16x8*)(Vbb + (size_t)(cf * 16 + li) * NP + ks * 32 + 8 * g);

    #pragma unroll 2
    for (int it = 0; it < NT; ++it) {
        const int j0 = it * 128;
        const int jn = (it == NT - 1) ? 0 : j0 + 128;   // branch-free clamp
        // ---- S^T (2 frags) ----
        f32x4 sA = MFMA16(kf0, qfS, zero);
        f32x4 sB = MFMA16(kf1, qfS, zero);
        kf0 = *(const bf16x8*)(kTb + (size_t)(jn + f0 * 16 + li) * CQ + 8 * g);
        kf1 = *(const bf16x8*)(kTb + (size_t)(jn + f1 * 16 + li) * CQ + 8 * g);
        float pa0 = exp2f(sA[0] - mrS), pa1 = exp2f(sA[1] - mrS);
        float pa2 = exp2f(sA[2] - mrS), pa3 = exp2f(sA[3] - mrS);
        float pb0 = exp2f(sB[0] - mrS), pb1 = exp2f(sB[1] - mrS);
        float pb2 = exp2f(sB[2] - mrS), pb3 = exp2f(sB[3] - mrS);
        ls += ((pa0 + pa1) + (pa2 + pa3)) + ((pb0 + pb1) + (pb2 + pb3));
        unsigned char* Pb = P[it & 1];
        u32x2 wA, wB;
        wA.x = pk_bf16(pa0, pa1); wA.y = pk_bf16(pa2, pa3);
        wB.x = pk_bf16(pb0, pb1); wB.y = pk_bf16(pb2, pb3);
        *(u32x2*)(Pb + pwOff0) = wA;
        *(u32x2*)(Pb + pwOff1) = wB;
        __syncthreads();
        // ---- prefetch next V (unconditional), then PV ----
        bf16x8 nv[2][4];
        #pragma unroll
        for (int cf = 0; cf < 2; ++cf)
            #pragma unroll
            for (int ks = 0; ks < 4; ++ks)
                nv[cf][ks] = *(const bf16x8*)(Vbb + (size_t)(cf * 16 + li) * NP + jn + ks * 32 + 8 * g);
        __builtin_amdgcn_s_setprio(1);
        #pragma unroll
        for (int ks = 0; ks < 4; ++ks) {
            const int o = (ks * 64 + 16 * g) ^ sw;
            bf16x8 p0 = *(const bf16x8*)(Pb + prRow0 + o);
            bf16x8 p1 = *(const bf16x8*)(Pb + prRow1 + o);
            acc[0][0] = MFMA16(p0, vf[0][ks], acc[0][0]);
            acc[0][1] = MFMA16(p0, vf[1][ks], acc[0][1]);
            acc[1][0] = MFMA16(p1, vf[0][ks], acc[1][0]);
            acc[1][1] = MFMA16(p1, vf[1][ks], acc[1][1]);
        }
        __builtin_amdgcn_s_setprio(0);
        #pragma unroll
        for (int cf = 0; cf < 2; ++cf)
            #pragma unroll
            for (int ks = 0; ks < 4; ++ks)
                vf[cf][ks] = nv[cf][ks];
    }

    // ---- denominator reduce (+ exact pad correction) ----
    ls += __shfl_xor(ls, 16); ls += __shfl_xor(ls, 32);
    if ((t & 63) < 16) red[w][li] = ls;
    __syncthreads();
    if (t < 32) {
        float s = red[(t >> 4) * 4 + 0][t & 15] + red[(t >> 4) * 4 + 1][t & 15]
                + red[(t >> 4) * 4 + 2][t & 15] + red[(t >> 4) * 4 + 3][t & 15];
        s -= 64.0f * exp2f(-qnorm[b * N_SP + i0 + t] * kmb);   // remove pad j's
        red_final[t] = s;
    }
    __syncthreads();

    // ---- epilogue: /ls, *gamma*INV_BOUND, + residual ----
    const float gsc = gamma_p[0] * INV_BOUND;
    #pragma unroll
    for (int qi = 0; qi < 2; ++qi) {
        f32x4 lsv = *(const f32x4*)(red_final + qi * 16 + 4 * g);
        f32x4 rinv;
        #pragma unroll
        for (int r = 0; r < 4; ++r) rinv[r] = gsc / lsv[r];
        #pragma unroll
        for (int cf = 0; cf < 2; ++cf) {
            const int c = cw + cf * 16 + li;
            const size_t base = ((size_t)b * C_CH + c) * N_SP + i0 + qi * 16 + 4 * g;
            float4 xv = *(const float4*)(x + base);
            float4 o;
            o.x = acc[qi][cf][0] * rinv[0] + xv.x;
            o.y = acc[qi][cf][1] * rinv[1] + xv.y;
            o.z = acc[qi][cf][2] * rinv[2] + xv.z;
            o.w = acc[qi][cf][3] * rinv[3] + xv.w;
            *(float4*)(out + base) = o;
        }
    }
}

// ---------------------------------------------------------------------------
extern "C" void kernel_launch(void* const* d_in, const int* in_sizes, int n_in,
                              void* d_out, int out_size, void* d_ws, size_t ws_size,
                              hipStream_t stream)
{
    const float* x  = (const float*)d_in[0];
    const float* Wq = (const float*)d_in[1];
    const float* bq = (const float*)d_in[2];
    const float* Wk = (const float*)d_in[3];
    const float* bk = (const float*)d_in[4];
    const float* Wv = (const float*)d_in[5];
    const float* bv = (const float*)d_in[6];
    const float* gm = (const float*)d_in[7];
    float* out = (float*)d_out;
    float* ws  = (float*)d_ws;

    float* scale = ws;                       // [0..3]
    float* kmax  = ws + 4;                   // [4..7], per-batch
    float* qnorm = ws + 8;                   // NB*N_SP floats
    u16* Wqb = (u16*)(ws + 8 + NB * N_SP);   // 16B-aligned (50208 % 16 == 0)
    u16* Wkb = Wqb + 32 * 256;
    u16* Wvb = Wkb + 32 * 256;
    u16* xT  = Wvb + 256 * 256;
    u16* qT  = xT + (size_t)NB * N_SP * C_CH;
    u16* kT  = qT + (size_t)NB * N_SP * CQ;
    u16* Vb  = kT + (size_t)NB * NP * CQ;

    (void)hipMemsetAsync(kmax, 0, NB * sizeof(float), stream);
    stage1_kernel<<<865, 256, 0, stream>>>(x, Wq, Wk, Wv, xT, Wqb, Wkb, Wvb, scale);
    qkv_mfma<<<984, 256, 0, stream>>>(xT, Wqb, Wkb, Wvb, bq, bk, bv, scale, qT, kT, Vb, qnorm, kmax);
    attn_mfma<<<392, 512, 0, stream>>>(qT, kT, Vb, x, gm, qnorm, kmax, out);
}